// Round 14
// baseline (58.615 us; speedup 1.0000x reference)
//
#include <hip/hip_runtime.h>

typedef unsigned short ushort_t;
typedef unsigned int uint_t;

constexpr int BSZ = 32;
constexpr int CH  = 64;
constexpr int HW  = 32 * 128;   // 4096
constexpr int NP  = 512;
constexpr int OSPLIT = 4;             // o-split across blocks
constexpr int OCHUNK = NP / OSPLIT;   // 128 o per block = 8 m-tiles
constexpr int MT     = OCHUNK / 16;   // 8
constexpr float EPS = 1e-8f;
constexpr float SCL = 2.8853900817779268f;   // 2*log2(e): pre-scale W,QB -> tanh needs no mul
constexpr float L2E = 1.4426950408889634f;   // log2(e)

using short8 = __attribute__((ext_vector_type(8))) short;   // 8 bf16 (4 VGPRs)
using f32x4  = __attribute__((ext_vector_type(4))) float;

__device__ __forceinline__ ushort_t f2bf(float f) {   // fp32 -> bf16 RNE
    uint_t u = __builtin_bit_cast(uint_t, f);
    u += 0x7FFFu + ((u >> 16) & 1u);
    return (ushort_t)(u >> 16);
}
__device__ __forceinline__ float bf2f(ushort_t b) {
    uint_t u = ((uint_t)b) << 16;
    return __builtin_bit_cast(float, u);
}

// async global->LDS (LDS dest = wave-uniform base + lane*size)
__device__ __forceinline__ void gld16(const void* g, void* l) {
    __builtin_amdgcn_global_load_lds(
        (const __attribute__((address_space(1))) void*)g,
        (__attribute__((address_space(3))) void*)l, 16, 0, 0);
}
__device__ __forceinline__ void gld4(const void* g, void* l) {
    __builtin_amdgcn_global_load_lds(
        (const __attribute__((address_space(1))) void*)g,
        (__attribute__((address_space(3))) void*)l, 4, 0, 0);
}

// K0: W' = SCL*Ua_w split to bf16 hi/lo in MFMA-frag order
//   fidx = mt*1024 + ks*512 + (kg*16+lm)*8 + j   (mt = o>>4 = 0..31)
// QB = SCL*(query+Ua_b); Va2 = -2*Va_w; SUMVW = sum(Va_w).
__global__ __launch_bounds__(256) void k_prep(
    const float* __restrict__ Ua_w, const float* __restrict__ Ua_b,
    const float* __restrict__ query, const float* __restrict__ Va_w,
    ushort_t* __restrict__ Whi_f, ushort_t* __restrict__ Wlo_f,
    float* __restrict__ QB, float* __restrict__ Va2, float* __restrict__ SUMVW)
{
    const int i = blockIdx.x * 256 + threadIdx.x;
    if (i < NP * CH) {
        const int o = i >> 6, ch = i & 63;
        const int mt = o >> 4, lm = o & 15;
        const int ks = ch >> 5, kg = (ch >> 3) & 3, j = ch & 7;
        const int fidx = mt * 1024 + ks * 512 + (kg * 16 + lm) * 8 + j;
        float x = Ua_w[i] * SCL;
        ushort_t h = f2bf(x);
        Whi_f[fidx] = h;
        Wlo_f[fidx] = f2bf(x - bf2f(h));
    }
    if (i < BSZ * NP) {
        QB[i] = SCL * (query[i] + Ua_b[i & (NP - 1)]);
    }
    if (i < NP) {
        Va2[i] = -2.0f * Va_w[i];
    }
    if (blockIdx.x == 0 && threadIdx.x < 64) {
        float s = 0.0f;
#pragma unroll
        for (int t = 0; t < 8; ++t) s += Va_w[threadIdx.x + t * 64];
#pragma unroll
        for (int off = 32; off > 0; off >>= 1) s += __shfl_down(s, off, 64);
        if (threadIdx.x == 0) SUMVW[0] = s;
    }
}

// K1: partial tanh-sums over an o-QUARTER (r13 size fix: full hi+lo W is
// 128KB, so a block stages a 32KB quarter, not the whole thing).
// 256-thread blocks, 33KB LDS -> 4 blocks/CU = 16 waves/CU. The m-loop has
// ZERO barriers and ZERO global ops (theory from r8-r12 evidence: per-chunk
// staging barriers convoy all waves into the same phase; serialized-issue
// floor is ~13us but measured 40us = stall-dominated). One barrier total.
// Wave shape: nt=2, split hi/lo accs (4 indep depth-3 chains, 52 VGPR).
// Grid 4096 = 32b x 32pc x 4r, r fastest -> same-key blocks adjacent (L2).
__global__ __launch_bounds__(256, 4) void k_scores(
    const float* __restrict__ key,
    const ushort_t* __restrict__ Whi_f, const ushort_t* __restrict__ Wlo_f,
    const float* __restrict__ QB, const float* __restrict__ Va2,
    float* __restrict__ e_part)
{
    const int bx = blockIdx.x;            // 0..4095
    const int r  = bx & 3;                // o-quarter (fastest)
    const int pc = (bx >> 2) & 31;        // 128-pos chunk
    const int b  = bx >> 7;               // batch
    const int wv = threadIdx.x >> 6;
    const int l  = threadIdx.x & 63;
    const int lm = l & 15;                // col-in-tile (A row / B,C col)
    const int kg = l >> 4;                // k-group
    const int p0 = pc * 128 + wv * 32;    // wave's first position

    __shared__ ushort_t Wl[16384];        // [hi 8K | lo 8K] ushorts: this r's 8 m-tiles
    __shared__ float qbl[OCHUNK];
    __shared__ float vwl[OCHUNK];

    // ---- stage W quarter: wave wv stages m-tiles {wv*2, wv*2+1} hi+lo ----
    const size_t wbase = ((size_t)r * MT + wv * 2) * 1024;   // ushort offset
#pragma unroll
    for (int t = 0; t < 4; ++t) {
        gld16(Whi_f + wbase + t * 512 + l * 8, &Wl[wv * 2048 + t * 512]);
        gld16(Wlo_f + wbase + t * 512 + l * 8, &Wl[8192 + wv * 2048 + t * 512]);
    }
    if (wv == 0) {                        // qb quarter: 128 floats
        gld4(QB + b * NP + r * OCHUNK + l, &qbl[0]);
        gld4(QB + b * NP + r * OCHUNK + 64 + l, &qbl[64]);
    }
    if (wv == 1) {                        // vw quarter: 128 floats
        gld4(Va2 + r * OCHUNK + l, &vwl[0]);
        gld4(Va2 + r * OCHUNK + 64 + l, &vwl[64]);
    }

    // ---- load + bf16-split this wave's key ONCE: B = key[b,:,p0..p0+31] ----
    short8 Bh[2][2], Bl8[2][2];
    const float* kb = key + (size_t)b * CH * HW;
#pragma unroll
    for (int nt = 0; nt < 2; ++nt) {
#pragma unroll
        for (int ks = 0; ks < 2; ++ks) {
#pragma unroll
            for (int j = 0; j < 8; ++j) {
                float x = kb[(size_t)(ks * 32 + kg * 8 + j) * HW + (p0 + nt * 16 + lm)];
                ushort_t h = f2bf(x);
                Bh[nt][ks][j]  = (short)h;
                Bl8[nt][ks][j] = (short)f2bf(x - bf2f(h));
            }
        }
    }

    __syncthreads();                      // all staging drained; ONLY barrier

    float P[2] = {0.0f, 0.0f};            // partial of (-2vw)*rcp

    // ---- 8 m-tiles, no barriers, no global ops ----
#pragma unroll 4
    for (int mt = 0; mt < MT; ++mt) {
        const short8 Ah0 = *(const short8*)&Wl[mt * 1024 + l * 8];
        const short8 Ah1 = *(const short8*)&Wl[mt * 1024 + 512 + l * 8];
        const short8 Al0 = *(const short8*)&Wl[8192 + mt * 1024 + l * 8];
        const short8 Al1 = *(const short8*)&Wl[8192 + mt * 1024 + 512 + l * 8];
        const f32x4 qb = *(const f32x4*)&qbl[mt * 16 + kg * 4];
        const f32x4 vw = *(const f32x4*)&vwl[mt * 16 + kg * 4];

        // 4 independent chains of depth 3; accA C-init = qb
        f32x4 accA[2], accB[2];
#pragma unroll
        for (int nt = 0; nt < 2; ++nt) {
            accA[nt] = __builtin_amdgcn_mfma_f32_16x16x32_bf16(Ah0, Bh[nt][0], qb, 0, 0, 0);
            accB[nt] = __builtin_amdgcn_mfma_f32_16x16x32_bf16(Ah1, Bh[nt][1],
                           (f32x4){0.f, 0.f, 0.f, 0.f}, 0, 0, 0);
        }
#pragma unroll
        for (int nt = 0; nt < 2; ++nt) {
            accA[nt] = __builtin_amdgcn_mfma_f32_16x16x32_bf16(Ah0, Bl8[nt][0], accA[nt], 0, 0, 0);
            accB[nt] = __builtin_amdgcn_mfma_f32_16x16x32_bf16(Ah1, Bl8[nt][1], accB[nt], 0, 0, 0);
        }
#pragma unroll
        for (int nt = 0; nt < 2; ++nt) {
            accA[nt] = __builtin_amdgcn_mfma_f32_16x16x32_bf16(Al0, Bh[nt][0], accA[nt], 0, 0, 0);
            accB[nt] = __builtin_amdgcn_mfma_f32_16x16x32_bf16(Al1, Bh[nt][1], accB[nt], 0, 0, 0);
        }

        // epilogue: s pre-scaled by 2*log2(e); P += (-2vw)*rcp(exp2(s)+1)
#pragma unroll
        for (int nt = 0; nt < 2; ++nt)
#pragma unroll
            for (int rr = 0; rr < 4; ++rr) {
                float s  = accA[nt][rr] + accB[nt][rr];
                float e  = __builtin_amdgcn_exp2f(s);
                float rc = __builtin_amdgcn_rcpf(e + 1.0f);
                P[nt] = fmaf(vw[rr], rc, P[nt]);
            }
    }

    // reduce over the 4 k-groups; kg==0 lanes hold the quarter-sums
#pragma unroll
    for (int nt = 0; nt < 2; ++nt) {
        P[nt] += __shfl_xor(P[nt], 16, 64);
        P[nt] += __shfl_xor(P[nt], 32, 64);
    }
    if (kg == 0) {
        float* dst = e_part + (size_t)r * (BSZ * HW) + (size_t)b * HW + p0;
        dst[lm]      = P[0];
        dst[16 + lm] = P[1];
    }
}

// K2: combine 4 o-quarters, exp, per-batch denominator.
__global__ __launch_bounds__(256) void k_denom(
    const float* __restrict__ e_part,
    const float* __restrict__ SUMVW, const float* __restrict__ Va_b,
    float* __restrict__ e_exp, float* __restrict__ inv_denom)
{
    const int b = blockIdx.x;
    const int tid = threadIdx.x;
    const float base = SUMVW[0] + Va_b[0];
    float s = 0.0f;
#pragma unroll
    for (int i = 0; i < HW / 256; ++i) {
        const int idx = b * HW + i * 256 + tid;
        float p = (e_part[idx] + e_part[BSZ * HW + idx]) +
                  (e_part[2 * BSZ * HW + idx] + e_part[3 * BSZ * HW + idx]);
        float e = __builtin_amdgcn_exp2f((p + base) * L2E);
        e_exp[idx] = e;
        s += e;
    }
#pragma unroll
    for (int off = 32; off > 0; off >>= 1) s += __shfl_down(s, off, 64);
    __shared__ float wsum[4];
    if ((tid & 63) == 0) wsum[tid >> 6] = s;
    __syncthreads();
    if (tid == 0) {
        float t = (wsum[0] + wsum[1]) + (wsum[2] + wsum[3]);
        inv_denom[b] = 1.0f / (t + EPS);
    }
}

// K3: out[b,c,p] = feature[b,c,p] * e_exp[b,p] * inv_denom[b]  (float4)
__global__ __launch_bounds__(256) void k_scale(
    const float* __restrict__ feature,
    const float* __restrict__ e_exp,
    const float* __restrict__ inv_denom,
    float* __restrict__ out)
{
    const int idx = blockIdx.x * 256 + threadIdx.x;   // float4 index
    const int pq = idx & (HW / 4 - 1);
    const int bc = idx >> 10;
    const int b  = bc >> 6;

    const float sc = inv_denom[b];
    const float4 e = ((const float4*)(e_exp + (size_t)b * HW))[pq];
    const float4 f = ((const float4*)feature)[idx];
    float4 o;
    o.x = f.x * (e.x * sc);
    o.y = f.y * (e.y * sc);
    o.z = f.z * (e.z * sc);
    o.w = f.w * (e.w * sc);
    ((float4*)out)[idx] = o;
}

extern "C" void kernel_launch(void* const* d_in, const int* in_sizes, int n_in,
                              void* d_out, int out_size, void* d_ws, size_t ws_size,
                              hipStream_t stream)
{
    const float* feature = (const float*)d_in[0];
    const float* query   = (const float*)d_in[1];
    const float* key     = (const float*)d_in[2];
    const float* Ua_w    = (const float*)d_in[3];
    const float* Ua_b    = (const float*)d_in[4];
    const float* Va_w    = (const float*)d_in[5];
    const float* Va_b    = (const float*)d_in[6];

    // workspace layout
    ushort_t* Whi_f = (ushort_t*)d_ws;                      // 512*64 frag-order
    ushort_t* Wlo_f = Whi_f + NP * CH;                      // 512*64
    float* QB        = (float*)(Wlo_f + NP * CH);           // 32*512
    float* Va2       = QB + BSZ * NP;                       // 512
    float* SUMVW     = Va2 + NP;                            // 1 (+pad)
    float* e_part    = SUMVW + 4;                           // 4*32*4096
    float* e_exp     = e_part + (size_t)OSPLIT * BSZ * HW;  // 32*4096
    float* inv_denom = e_exp + BSZ * HW;                    // 32

    k_prep<<<(NP * CH) / 256, 256, 0, stream>>>(
        Ua_w, Ua_b, query, Va_w, Whi_f, Wlo_f, QB, Va2, SUMVW);
    k_scores<<<BSZ * 32 * OSPLIT, 256, 0, stream>>>(
        key, Whi_f, Wlo_f, QB, Va2, e_part);
    k_denom<<<BSZ, 256, 0, stream>>>(e_part, SUMVW, Va_b, e_exp, inv_denom);
    k_scale<<<(BSZ * CH * HW / 4) / 256, 256, 0, stream>>>(
        feature, e_exp, inv_denom, (float*)d_out);
}

// Round 15
// 57.319 us; speedup vs baseline: 1.0226x; 1.0226x over previous
//
#include <hip/hip_runtime.h>

typedef unsigned short ushort_t;
typedef unsigned int uint_t;

constexpr int BSZ = 32;
constexpr int CH  = 64;
constexpr int HW  = 32 * 128;   // 4096
constexpr int NP  = 512;
constexpr int OSPLIT = 4;             // o-split across blocks
constexpr int OCHUNK = NP / OSPLIT;   // 128 o per block = 8 m-tiles
constexpr int MT     = OCHUNK / 16;   // 8
constexpr float EPS = 1e-8f;
constexpr float SCL = 2.8853900817779268f;   // 2*log2(e): pre-scale W,QB -> tanh needs no mul
constexpr float L2E = 1.4426950408889634f;   // log2(e)

using short8 = __attribute__((ext_vector_type(8))) short;   // 8 bf16 (4 VGPRs)
using f32x4  = __attribute__((ext_vector_type(4))) float;

__device__ __forceinline__ ushort_t f2bf(float f) {   // fp32 -> bf16 RNE
    uint_t u = __builtin_bit_cast(uint_t, f);
    u += 0x7FFFu + ((u >> 16) & 1u);
    return (ushort_t)(u >> 16);
}
__device__ __forceinline__ float bf2f(ushort_t b) {
    uint_t u = ((uint_t)b) << 16;
    return __builtin_bit_cast(float, u);
}

// async global->LDS (LDS dest = wave-uniform base + lane*size)
__device__ __forceinline__ void gld16(const void* g, void* l) {
    __builtin_amdgcn_global_load_lds(
        (const __attribute__((address_space(1))) void*)g,
        (__attribute__((address_space(3))) void*)l, 16, 0, 0);
}
__device__ __forceinline__ void gld4(const void* g, void* l) {
    __builtin_amdgcn_global_load_lds(
        (const __attribute__((address_space(1))) void*)g,
        (__attribute__((address_space(3))) void*)l, 4, 0, 0);
}

// K0: W' = SCL*Ua_w split to bf16 hi/lo in MFMA-frag order
//   fidx = mt*1024 + ks*512 + (kg*16+lm)*8 + j   (mt = o>>4 = 0..31)
// QB = SCL*(query+Ua_b); Va2 = -2*Va_w; SUMVW = sum(Va_w).
__global__ __launch_bounds__(256) void k_prep(
    const float* __restrict__ Ua_w, const float* __restrict__ Ua_b,
    const float* __restrict__ query, const float* __restrict__ Va_w,
    ushort_t* __restrict__ Whi_f, ushort_t* __restrict__ Wlo_f,
    float* __restrict__ QB, float* __restrict__ Va2, float* __restrict__ SUMVW)
{
    const int i = blockIdx.x * 256 + threadIdx.x;
    if (i < NP * CH) {
        const int o = i >> 6, ch = i & 63;
        const int mt = o >> 4, lm = o & 15;
        const int ks = ch >> 5, kg = (ch >> 3) & 3, j = ch & 7;
        const int fidx = mt * 1024 + ks * 512 + (kg * 16 + lm) * 8 + j;
        float x = Ua_w[i] * SCL;
        ushort_t h = f2bf(x);
        Whi_f[fidx] = h;
        Wlo_f[fidx] = f2bf(x - bf2f(h));
    }
    if (i < BSZ * NP) {
        QB[i] = SCL * (query[i] + Ua_b[i & (NP - 1)]);
    }
    if (i < NP) {
        Va2[i] = -2.0f * Va_w[i];
    }
    if (blockIdx.x == 0 && threadIdx.x < 64) {
        float s = 0.0f;
#pragma unroll
        for (int t = 0; t < 8; ++t) s += Va_w[threadIdx.x + t * 64];
#pragma unroll
        for (int off = 32; off > 0; off >>= 1) s += __shfl_down(s, off, 64);
        if (threadIdx.x == 0) SUMVW[0] = s;
    }
}

// K1: partial tanh-sums over an o-quarter. Identical to r14 EXCEPT:
// (1) STAGGERED m-loop start per wave: s0=((bx&3)+wv*2)&7. r14 post-mortem:
//     serialized pipe-sum (MFMA 12.4us at the real 19.4cyc/mfma rate + trans
//     ~7-14 + VALU ~5 + LDS ~10) equals the measured 40us -- waves are
//     phase-locked (identical code, same start), so MFMA/VALU/LDS time-share
//     instead of cross-wave overlapping (m114 proves they CAN overlap).
//     Rotation de-phases waves by ~2 m-tiles (~500cyc); operands all in LDS.
// (2) s_setprio(1) around the MFMA cluster (T5: pays only with role
//     diversity, which the stagger creates).
__global__ __launch_bounds__(256, 4) void k_scores(
    const float* __restrict__ key,
    const ushort_t* __restrict__ Whi_f, const ushort_t* __restrict__ Wlo_f,
    const float* __restrict__ QB, const float* __restrict__ Va2,
    float* __restrict__ e_part)
{
    const int bx = blockIdx.x;            // 0..4095
    const int r  = bx & 3;                // o-quarter (fastest)
    const int pc = (bx >> 2) & 31;        // 128-pos chunk
    const int b  = bx >> 7;               // batch
    const int wv = threadIdx.x >> 6;
    const int l  = threadIdx.x & 63;
    const int lm = l & 15;                // col-in-tile (A row / B,C col)
    const int kg = l >> 4;                // k-group
    const int p0 = pc * 128 + wv * 32;    // wave's first position
    const int s0 = ((bx & 3) + wv * 2) & 7;   // stagger: de-phase waves

    __shared__ ushort_t Wl[16384];        // [hi 8K | lo 8K] ushorts: this r's 8 m-tiles
    __shared__ float qbl[OCHUNK];
    __shared__ float vwl[OCHUNK];

    // ---- stage W quarter: wave wv stages m-tiles {wv*2, wv*2+1} hi+lo ----
    const size_t wbase = ((size_t)r * MT + wv * 2) * 1024;   // ushort offset
#pragma unroll
    for (int t = 0; t < 4; ++t) {
        gld16(Whi_f + wbase + t * 512 + l * 8, &Wl[wv * 2048 + t * 512]);
        gld16(Wlo_f + wbase + t * 512 + l * 8, &Wl[8192 + wv * 2048 + t * 512]);
    }
    if (wv == 0) {                        // qb quarter: 128 floats
        gld4(QB + b * NP + r * OCHUNK + l, &qbl[0]);
        gld4(QB + b * NP + r * OCHUNK + 64 + l, &qbl[64]);
    }
    if (wv == 1) {                        // vw quarter: 128 floats
        gld4(Va2 + r * OCHUNK + l, &vwl[0]);
        gld4(Va2 + r * OCHUNK + 64 + l, &vwl[64]);
    }

    // ---- load + bf16-split this wave's key ONCE: B = key[b,:,p0..p0+31] ----
    short8 Bh[2][2], Bl8[2][2];
    const float* kb = key + (size_t)b * CH * HW;
#pragma unroll
    for (int nt = 0; nt < 2; ++nt) {
#pragma unroll
        for (int ks = 0; ks < 2; ++ks) {
#pragma unroll
            for (int j = 0; j < 8; ++j) {
                float x = kb[(size_t)(ks * 32 + kg * 8 + j) * HW + (p0 + nt * 16 + lm)];
                ushort_t h = f2bf(x);
                Bh[nt][ks][j]  = (short)h;
                Bl8[nt][ks][j] = (short)f2bf(x - bf2f(h));
            }
        }
    }

    __syncthreads();                      // all staging drained; ONLY barrier

    float P[2] = {0.0f, 0.0f};            // partial of (-2vw)*rcp

    // ---- 8 m-tiles, rotated start, no barriers, no global ops ----
#pragma unroll 4
    for (int i = 0; i < MT; ++i) {
        const int mt = (i + s0) & 7;
        const short8 Ah0 = *(const short8*)&Wl[mt * 1024 + l * 8];
        const short8 Ah1 = *(const short8*)&Wl[mt * 1024 + 512 + l * 8];
        const short8 Al0 = *(const short8*)&Wl[8192 + mt * 1024 + l * 8];
        const short8 Al1 = *(const short8*)&Wl[8192 + mt * 1024 + 512 + l * 8];
        const f32x4 qb = *(const f32x4*)&qbl[mt * 16 + kg * 4];
        const f32x4 vw = *(const f32x4*)&vwl[mt * 16 + kg * 4];

        // 4 independent chains of depth 3; accA C-init = qb
        f32x4 accA[2], accB[2];
        __builtin_amdgcn_s_setprio(1);
#pragma unroll
        for (int nt = 0; nt < 2; ++nt) {
            accA[nt] = __builtin_amdgcn_mfma_f32_16x16x32_bf16(Ah0, Bh[nt][0], qb, 0, 0, 0);
            accB[nt] = __builtin_amdgcn_mfma_f32_16x16x32_bf16(Ah1, Bh[nt][1],
                           (f32x4){0.f, 0.f, 0.f, 0.f}, 0, 0, 0);
        }
#pragma unroll
        for (int nt = 0; nt < 2; ++nt) {
            accA[nt] = __builtin_amdgcn_mfma_f32_16x16x32_bf16(Ah0, Bl8[nt][0], accA[nt], 0, 0, 0);
            accB[nt] = __builtin_amdgcn_mfma_f32_16x16x32_bf16(Ah1, Bl8[nt][1], accB[nt], 0, 0, 0);
        }
#pragma unroll
        for (int nt = 0; nt < 2; ++nt) {
            accA[nt] = __builtin_amdgcn_mfma_f32_16x16x32_bf16(Al0, Bh[nt][0], accA[nt], 0, 0, 0);
            accB[nt] = __builtin_amdgcn_mfma_f32_16x16x32_bf16(Al1, Bh[nt][1], accB[nt], 0, 0, 0);
        }
        __builtin_amdgcn_s_setprio(0);

        // epilogue: s pre-scaled by 2*log2(e); P += (-2vw)*rcp(exp2(s)+1)
#pragma unroll
        for (int nt = 0; nt < 2; ++nt)
#pragma unroll
            for (int rr = 0; rr < 4; ++rr) {
                float s  = accA[nt][rr] + accB[nt][rr];
                float e  = __builtin_amdgcn_exp2f(s);
                float rc = __builtin_amdgcn_rcpf(e + 1.0f);
                P[nt] = fmaf(vw[rr], rc, P[nt]);
            }
    }

    // reduce over the 4 k-groups; kg==0 lanes hold the quarter-sums
#pragma unroll
    for (int nt = 0; nt < 2; ++nt) {
        P[nt] += __shfl_xor(P[nt], 16, 64);
        P[nt] += __shfl_xor(P[nt], 32, 64);
    }
    if (kg == 0) {
        float* dst = e_part + (size_t)r * (BSZ * HW) + (size_t)b * HW + p0;
        dst[lm]      = P[0];
        dst[16 + lm] = P[1];
    }
}

// K2: combine 4 o-quarters, exp, per-batch denominator.
__global__ __launch_bounds__(256) void k_denom(
    const float* __restrict__ e_part,
    const float* __restrict__ SUMVW, const float* __restrict__ Va_b,
    float* __restrict__ e_exp, float* __restrict__ inv_denom)
{
    const int b = blockIdx.x;
    const int tid = threadIdx.x;
    const float base = SUMVW[0] + Va_b[0];
    float s = 0.0f;
#pragma unroll
    for (int i = 0; i < HW / 256; ++i) {
        const int idx = b * HW + i * 256 + tid;
        float p = (e_part[idx] + e_part[BSZ * HW + idx]) +
                  (e_part[2 * BSZ * HW + idx] + e_part[3 * BSZ * HW + idx]);
        float e = __builtin_amdgcn_exp2f((p + base) * L2E);
        e_exp[idx] = e;
        s += e;
    }
#pragma unroll
    for (int off = 32; off > 0; off >>= 1) s += __shfl_down(s, off, 64);
    __shared__ float wsum[4];
    if ((tid & 63) == 0) wsum[tid >> 6] = s;
    __syncthreads();
    if (tid == 0) {
        float t = (wsum[0] + wsum[1]) + (wsum[2] + wsum[3]);
        inv_denom[b] = 1.0f / (t + EPS);
    }
}

// K3: out[b,c,p] = feature[b,c,p] * e_exp[b,p] * inv_denom[b]  (float4)
__global__ __launch_bounds__(256) void k_scale(
    const float* __restrict__ feature,
    const float* __restrict__ e_exp,
    const float* __restrict__ inv_denom,
    float* __restrict__ out)
{
    const int idx = blockIdx.x * 256 + threadIdx.x;   // float4 index
    const int pq = idx & (HW / 4 - 1);
    const int bc = idx >> 10;
    const int b  = bc >> 6;

    const float sc = inv_denom[b];
    const float4 e = ((const float4*)(e_exp + (size_t)b * HW))[pq];
    const float4 f = ((const float4*)feature)[idx];
    float4 o;
    o.x = f.x * (e.x * sc);
    o.y = f.y * (e.y * sc);
    o.z = f.z * (e.z * sc);
    o.w = f.w * (e.w * sc);
    ((float4*)out)[idx] = o;
}

extern "C" void kernel_launch(void* const* d_in, const int* in_sizes, int n_in,
                              void* d_out, int out_size, void* d_ws, size_t ws_size,
                              hipStream_t stream)
{
    const float* feature = (const float*)d_in[0];
    const float* query   = (const float*)d_in[1];
    const float* key     = (const float*)d_in[2];
    const float* Ua_w    = (const float*)d_in[3];
    const float* Ua_b    = (const float*)d_in[4];
    const float* Va_w    = (const float*)d_in[5];
    const float* Va_b    = (const float*)d_in[6];

    // workspace layout
    ushort_t* Whi_f = (ushort_t*)d_ws;                      // 512*64 frag-order
    ushort_t* Wlo_f = Whi_f + NP * CH;                      // 512*64
    float* QB        = (float*)(Wlo_f + NP * CH);           // 32*512
    float* Va2       = QB + BSZ * NP;                       // 512
    float* SUMVW     = Va2 + NP;                            // 1 (+pad)
    float* e_part    = SUMVW + 4;                           // 4*32*4096
    float* e_exp     = e_part + (size_t)OSPLIT * BSZ * HW;  // 32*4096
    float* inv_denom = e_exp + BSZ * HW;                    // 32

    k_prep<<<(NP * CH) / 256, 256, 0, stream>>>(
        Ua_w, Ua_b, query, Va_w, Whi_f, Wlo_f, QB, Va2, SUMVW);
    k_scores<<<BSZ * 32 * OSPLIT, 256, 0, stream>>>(
        key, Whi_f, Wlo_f, QB, Va2, e_part);
    k_denom<<<BSZ, 256, 0, stream>>>(e_part, SUMVW, Va_b, e_exp, inv_denom);
    k_scale<<<(BSZ * CH * HW / 4) / 256, 256, 0, stream>>>(
        feature, e_exp, inv_denom, (float*)d_out);
}

// Round 16
// 55.099 us; speedup vs baseline: 1.0638x; 1.0403x over previous
//
#include <hip/hip_runtime.h>

typedef unsigned short ushort_t;
typedef unsigned int uint_t;

constexpr int BSZ = 32;
constexpr int CH  = 64;
constexpr int HW  = 32 * 128;   // 4096
constexpr int NP  = 512;
constexpr int OSPLIT = 4;             // o-split across blocks
constexpr int OCHUNK = NP / OSPLIT;   // 128 o per block = 8 m-tiles
constexpr int MT     = OCHUNK / 16;   // 8
constexpr float EPS = 1e-8f;
constexpr float SCL = 2.8853900817779268f;   // 2*log2(e): pre-scale W,QB -> tanh needs no mul
constexpr float L2E = 1.4426950408889634f;   // log2(e)

using short8 = __attribute__((ext_vector_type(8))) short;   // 8 bf16 (4 VGPRs)
using f32x4  = __attribute__((ext_vector_type(4))) float;

__device__ __forceinline__ ushort_t f2bf(float f) {   // fp32 -> bf16 RNE
    uint_t u = __builtin_bit_cast(uint_t, f);
    u += 0x7FFFu + ((u >> 16) & 1u);
    return (ushort_t)(u >> 16);
}
__device__ __forceinline__ float bf2f(ushort_t b) {
    uint_t u = ((uint_t)b) << 16;
    return __builtin_bit_cast(float, u);
}

// async global->LDS (LDS dest = wave-uniform base + lane*size)
__device__ __forceinline__ void gld16(const void* g, void* l) {
    __builtin_amdgcn_global_load_lds(
        (const __attribute__((address_space(1))) void*)g,
        (__attribute__((address_space(3))) void*)l, 16, 0, 0);
}
__device__ __forceinline__ void gld4(const void* g, void* l) {
    __builtin_amdgcn_global_load_lds(
        (const __attribute__((address_space(1))) void*)g,
        (__attribute__((address_space(3))) void*)l, 4, 0, 0);
}

// K0: W' = SCL*Ua_w split to bf16 hi/lo in MFMA-frag order
//   fidx = mt*1024 + ks*512 + (kg*16+lm)*8 + j   (mt = o>>4 = 0..31)
// QB = SCL*(query+Ua_b); Va2 = -2*Va_w; SUMVW = sum(Va_w).
__global__ __launch_bounds__(256) void k_prep(
    const float* __restrict__ Ua_w, const float* __restrict__ Ua_b,
    const float* __restrict__ query, const float* __restrict__ Va_w,
    ushort_t* __restrict__ Whi_f, ushort_t* __restrict__ Wlo_f,
    float* __restrict__ QB, float* __restrict__ Va2, float* __restrict__ SUMVW)
{
    const int i = blockIdx.x * 256 + threadIdx.x;
    if (i < NP * CH) {
        const int o = i >> 6, ch = i & 63;
        const int mt = o >> 4, lm = o & 15;
        const int ks = ch >> 5, kg = (ch >> 3) & 3, j = ch & 7;
        const int fidx = mt * 1024 + ks * 512 + (kg * 16 + lm) * 8 + j;
        float x = Ua_w[i] * SCL;
        ushort_t h = f2bf(x);
        Whi_f[fidx] = h;
        Wlo_f[fidx] = f2bf(x - bf2f(h));
    }
    if (i < BSZ * NP) {
        QB[i] = SCL * (query[i] + Ua_b[i & (NP - 1)]);
    }
    if (i < NP) {
        Va2[i] = -2.0f * Va_w[i];
    }
    if (blockIdx.x == 0 && threadIdx.x < 64) {
        float s = 0.0f;
#pragma unroll
        for (int t = 0; t < 8; ++t) s += Va_w[threadIdx.x + t * 64];
#pragma unroll
        for (int off = 32; off > 0; off >>= 1) s += __shfl_down(s, off, 64);
        if (threadIdx.x == 0) SUMVW[0] = s;
    }
}

// K1: partial tanh-sums over an o-quarter. r15 + two aimed changes:
// (1) TRUE time stagger: s_sleep(wv*5) after the barrier (~320cyc/wave).
//     r15's index-rotation changed WHICH mt each wave ran, not WHEN --
//     instruction timing stayed identical, so waves stayed phase-locked and
//     MFMA/VALU/trans/LDS time-shared (pipe-sum == measured 40us).
// (2) XCD-grouping swizzle: bx = G*32 + r*8 + x so the 4 r-siblings sharing
//     a key chunk have equal bx%8 -> same XCD L2 (r15 FETCH=65.8MB ~ 2x key:
//     round-robin dispatch spread siblings over 4 XCDs).
__global__ __launch_bounds__(256, 4) void k_scores(
    const float* __restrict__ key,
    const ushort_t* __restrict__ Whi_f, const ushort_t* __restrict__ Wlo_f,
    const float* __restrict__ QB, const float* __restrict__ Va2,
    float* __restrict__ e_part)
{
    const int bx = blockIdx.x;            // 0..4095
    const int x  = bx & 7;                // XCD slot
    const int r  = (bx >> 3) & 3;         // o-quarter (siblings 8 apart: same XCD)
    const int G  = bx >> 5;
    const int g  = G * 8 + x;             // (b,pc) group 0..1023
    const int b  = g >> 5;                // batch
    const int pc = g & 31;                // 128-pos chunk
    const int wv = threadIdx.x >> 6;
    const int l  = threadIdx.x & 63;
    const int lm = l & 15;                // col-in-tile (A row / B,C col)
    const int kg = l >> 4;                // k-group
    const int p0 = pc * 128 + wv * 32;    // wave's first position

    __shared__ ushort_t Wl[16384];        // [hi 8K | lo 8K] ushorts: this r's 8 m-tiles
    __shared__ float qbl[OCHUNK];
    __shared__ float vwl[OCHUNK];

    // ---- stage W quarter: wave wv stages m-tiles {wv*2, wv*2+1} hi+lo ----
    const size_t wbase = ((size_t)r * MT + wv * 2) * 1024;   // ushort offset
#pragma unroll
    for (int t = 0; t < 4; ++t) {
        gld16(Whi_f + wbase + t * 512 + l * 8, &Wl[wv * 2048 + t * 512]);
        gld16(Wlo_f + wbase + t * 512 + l * 8, &Wl[8192 + wv * 2048 + t * 512]);
    }
    if (wv == 0) {                        // qb quarter: 128 floats
        gld4(QB + b * NP + r * OCHUNK + l, &qbl[0]);
        gld4(QB + b * NP + r * OCHUNK + 64 + l, &qbl[64]);
    }
    if (wv == 1) {                        // vw quarter: 128 floats
        gld4(Va2 + r * OCHUNK + l, &vwl[0]);
        gld4(Va2 + r * OCHUNK + 64 + l, &vwl[64]);
    }

    // ---- load + bf16-split this wave's key ONCE: B = key[b,:,p0..p0+31] ----
    short8 Bh[2][2], Bl8[2][2];
    const float* kb = key + (size_t)b * CH * HW;
#pragma unroll
    for (int nt = 0; nt < 2; ++nt) {
#pragma unroll
        for (int ks = 0; ks < 2; ++ks) {
#pragma unroll
            for (int j = 0; j < 8; ++j) {
                float x2 = kb[(size_t)(ks * 32 + kg * 8 + j) * HW + (p0 + nt * 16 + lm)];
                ushort_t h = f2bf(x2);
                Bh[nt][ks][j]  = (short)h;
                Bl8[nt][ks][j] = (short)f2bf(x2 - bf2f(h));
            }
        }
    }

    __syncthreads();                      // all staging drained; ONLY barrier

    // TRUE time-domain stagger: offset each wave's loop start by ~320 cyc
    if (wv == 1) __builtin_amdgcn_s_sleep(5);
    else if (wv == 2) __builtin_amdgcn_s_sleep(10);
    else if (wv == 3) __builtin_amdgcn_s_sleep(15);

    float P[2] = {0.0f, 0.0f};            // partial of (-2vw)*rcp

    // ---- 8 m-tiles, no barriers, no global ops ----
#pragma unroll 4
    for (int mt = 0; mt < MT; ++mt) {
        const short8 Ah0 = *(const short8*)&Wl[mt * 1024 + l * 8];
        const short8 Ah1 = *(const short8*)&Wl[mt * 1024 + 512 + l * 8];
        const short8 Al0 = *(const short8*)&Wl[8192 + mt * 1024 + l * 8];
        const short8 Al1 = *(const short8*)&Wl[8192 + mt * 1024 + 512 + l * 8];
        const f32x4 qb = *(const f32x4*)&qbl[mt * 16 + kg * 4];
        const f32x4 vw = *(const f32x4*)&vwl[mt * 16 + kg * 4];

        // 4 independent chains of depth 3; accA C-init = qb
        f32x4 accA[2], accB[2];
        __builtin_amdgcn_s_setprio(1);
#pragma unroll
        for (int nt = 0; nt < 2; ++nt) {
            accA[nt] = __builtin_amdgcn_mfma_f32_16x16x32_bf16(Ah0, Bh[nt][0], qb, 0, 0, 0);
            accB[nt] = __builtin_amdgcn_mfma_f32_16x16x32_bf16(Ah1, Bh[nt][1],
                           (f32x4){0.f, 0.f, 0.f, 0.f}, 0, 0, 0);
        }
#pragma unroll
        for (int nt = 0; nt < 2; ++nt) {
            accA[nt] = __builtin_amdgcn_mfma_f32_16x16x32_bf16(Ah0, Bl8[nt][0], accA[nt], 0, 0, 0);
            accB[nt] = __builtin_amdgcn_mfma_f32_16x16x32_bf16(Ah1, Bl8[nt][1], accB[nt], 0, 0, 0);
        }
#pragma unroll
        for (int nt = 0; nt < 2; ++nt) {
            accA[nt] = __builtin_amdgcn_mfma_f32_16x16x32_bf16(Al0, Bh[nt][0], accA[nt], 0, 0, 0);
            accB[nt] = __builtin_amdgcn_mfma_f32_16x16x32_bf16(Al1, Bh[nt][1], accB[nt], 0, 0, 0);
        }
        __builtin_amdgcn_s_setprio(0);

        // epilogue: s pre-scaled by 2*log2(e); P += (-2vw)*rcp(exp2(s)+1)
#pragma unroll
        for (int nt = 0; nt < 2; ++nt)
#pragma unroll
            for (int rr = 0; rr < 4; ++rr) {
                float s  = accA[nt][rr] + accB[nt][rr];
                float e  = __builtin_amdgcn_exp2f(s);
                float rc = __builtin_amdgcn_rcpf(e + 1.0f);
                P[nt] = fmaf(vw[rr], rc, P[nt]);
            }
    }

    // reduce over the 4 k-groups; kg==0 lanes hold the quarter-sums
#pragma unroll
    for (int nt = 0; nt < 2; ++nt) {
        P[nt] += __shfl_xor(P[nt], 16, 64);
        P[nt] += __shfl_xor(P[nt], 32, 64);
    }
    if (kg == 0) {
        float* dst = e_part + (size_t)r * (BSZ * HW) + (size_t)b * HW + p0;
        dst[lm]      = P[0];
        dst[16 + lm] = P[1];
    }
}

// K2: combine 4 o-quarters, exp, per-batch denominator.
__global__ __launch_bounds__(256) void k_denom(
    const float* __restrict__ e_part,
    const float* __restrict__ SUMVW, const float* __restrict__ Va_b,
    float* __restrict__ e_exp, float* __restrict__ inv_denom)
{
    const int b = blockIdx.x;
    const int tid = threadIdx.x;
    const float base = SUMVW[0] + Va_b[0];
    float s = 0.0f;
#pragma unroll
    for (int i = 0; i < HW / 256; ++i) {
        const int idx = b * HW + i * 256 + tid;
        float p = (e_part[idx] + e_part[BSZ * HW + idx]) +
                  (e_part[2 * BSZ * HW + idx] + e_part[3 * BSZ * HW + idx]);
        float e = __builtin_amdgcn_exp2f((p + base) * L2E);
        e_exp[idx] = e;
        s += e;
    }
#pragma unroll
    for (int off = 32; off > 0; off >>= 1) s += __shfl_down(s, off, 64);
    __shared__ float wsum[4];
    if ((tid & 63) == 0) wsum[tid >> 6] = s;
    __syncthreads();
    if (tid == 0) {
        float t = (wsum[0] + wsum[1]) + (wsum[2] + wsum[3]);
        inv_denom[b] = 1.0f / (t + EPS);
    }
}

// K3: out[b,c,p] = feature[b,c,p] * e_exp[b,p] * inv_denom[b]  (float4)
__global__ __launch_bounds__(256) void k_scale(
    const float* __restrict__ feature,
    const float* __restrict__ e_exp,
    const float* __restrict__ inv_denom,
    float* __restrict__ out)
{
    const int idx = blockIdx.x * 256 + threadIdx.x;   // float4 index
    const int pq = idx & (HW / 4 - 1);
    const int bc = idx >> 10;
    const int b  = bc >> 6;

    const float sc = inv_denom[b];
    const float4 e = ((const float4*)(e_exp + (size_t)b * HW))[pq];
    const float4 f = ((const float4*)feature)[idx];
    float4 o;
    o.x = f.x * (e.x * sc);
    o.y = f.y * (e.y * sc);
    o.z = f.z * (e.z * sc);
    o.w = f.w * (e.w * sc);
    ((float4*)out)[idx] = o;
}

extern "C" void kernel_launch(void* const* d_in, const int* in_sizes, int n_in,
                              void* d_out, int out_size, void* d_ws, size_t ws_size,
                              hipStream_t stream)
{
    const float* feature = (const float*)d_in[0];
    const float* query   = (const float*)d_in[1];
    const float* key     = (const float*)d_in[2];
    const float* Ua_w    = (const float*)d_in[3];
    const float* Ua_b    = (const float*)d_in[4];
    const float* Va_w    = (const float*)d_in[5];
    const float* Va_b    = (const float*)d_in[6];

    // workspace layout
    ushort_t* Whi_f = (ushort_t*)d_ws;                      // 512*64 frag-order
    ushort_t* Wlo_f = Whi_f + NP * CH;                      // 512*64
    float* QB        = (float*)(Wlo_f + NP * CH);           // 32*512
    float* Va2       = QB + BSZ * NP;                       // 512
    float* SUMVW     = Va2 + NP;                            // 1 (+pad)
    float* e_part    = SUMVW + 4;                           // 4*32*4096
    float* e_exp     = e_part + (size_t)OSPLIT * BSZ * HW;  // 32*4096
    float* inv_denom = e_exp + BSZ * HW;                    // 32

    k_prep<<<(NP * CH) / 256, 256, 0, stream>>>(
        Ua_w, Ua_b, query, Va_w, Whi_f, Wlo_f, QB, Va2, SUMVW);
    k_scores<<<BSZ * 32 * OSPLIT, 256, 0, stream>>>(
        key, Whi_f, Wlo_f, QB, Va2, e_part);
    k_denom<<<BSZ, 256, 0, stream>>>(e_part, SUMVW, Va_b, e_exp, inv_denom);
    k_scale<<<(BSZ * CH * HW / 4) / 256, 256, 0, stream>>>(
        feature, e_exp, inv_denom, (float*)d_out);
}

// Round 17
// 54.189 us; speedup vs baseline: 1.0817x; 1.0168x over previous
//
#include <hip/hip_runtime.h>

typedef unsigned short ushort_t;
typedef unsigned int uint_t;

constexpr int BSZ = 32;
constexpr int CH  = 64;
constexpr int HW  = 32 * 128;   // 4096
constexpr int NP  = 512;
constexpr int OSPLIT = 4;             // o-split across blocks
constexpr int OCHUNK = NP / OSPLIT;   // 128 o per block = 8 m-tiles
constexpr int MT     = OCHUNK / 16;   // 8
constexpr float EPS = 1e-8f;
constexpr float SCL = 2.8853900817779268f;   // 2*log2(e): pre-scale W,QB -> tanh needs no mul
constexpr float L2E = 1.4426950408889634f;   // log2(e)

using short8 = __attribute__((ext_vector_type(8))) short;   // 8 bf16 (4 VGPRs)
using f32x4  = __attribute__((ext_vector_type(4))) float;

__device__ __forceinline__ ushort_t f2bf(float f) {   // fp32 -> bf16 RNE
    uint_t u = __builtin_bit_cast(uint_t, f);
    u += 0x7FFFu + ((u >> 16) & 1u);
    return (ushort_t)(u >> 16);
}
__device__ __forceinline__ float bf2f(ushort_t b) {
    uint_t u = ((uint_t)b) << 16;
    return __builtin_bit_cast(float, u);
}

// async global->LDS (LDS dest = wave-uniform base + lane*size)
__device__ __forceinline__ void gld16(const void* g, void* l) {
    __builtin_amdgcn_global_load_lds(
        (const __attribute__((address_space(1))) void*)g,
        (__attribute__((address_space(3))) void*)l, 16, 0, 0);
}
__device__ __forceinline__ void gld4(const void* g, void* l) {
    __builtin_amdgcn_global_load_lds(
        (const __attribute__((address_space(1))) void*)g,
        (__attribute__((address_space(3))) void*)l, 4, 0, 0);
}

// K0: W' = SCL*Ua_w split to bf16 hi/lo in MFMA-frag order
//   fidx = mt*1024 + ks*512 + (kg*16+lm)*8 + j   (mt = o>>4 = 0..31)
// QB = SCL*(query+Ua_b); Va2 = -2*Va_w; SUMVW = sum(Va_w).
__global__ __launch_bounds__(256) void k_prep(
    const float* __restrict__ Ua_w, const float* __restrict__ Ua_b,
    const float* __restrict__ query, const float* __restrict__ Va_w,
    ushort_t* __restrict__ Whi_f, ushort_t* __restrict__ Wlo_f,
    float* __restrict__ QB, float* __restrict__ Va2, float* __restrict__ SUMVW)
{
    const int i = blockIdx.x * 256 + threadIdx.x;
    if (i < NP * CH) {
        const int o = i >> 6, ch = i & 63;
        const int mt = o >> 4, lm = o & 15;
        const int ks = ch >> 5, kg = (ch >> 3) & 3, j = ch & 7;
        const int fidx = mt * 1024 + ks * 512 + (kg * 16 + lm) * 8 + j;
        float x = Ua_w[i] * SCL;
        ushort_t h = f2bf(x);
        Whi_f[fidx] = h;
        Wlo_f[fidx] = f2bf(x - bf2f(h));
    }
    if (i < BSZ * NP) {
        QB[i] = SCL * (query[i] + Ua_b[i & (NP - 1)]);
    }
    if (i < NP) {
        Va2[i] = -2.0f * Va_w[i];
    }
    if (blockIdx.x == 0 && threadIdx.x < 64) {
        float s = 0.0f;
#pragma unroll
        for (int t = 0; t < 8; ++t) s += Va_w[threadIdx.x + t * 64];
#pragma unroll
        for (int off = 32; off > 0; off >>= 1) s += __shfl_down(s, off, 64);
        if (threadIdx.x == 0) SUMVW[0] = s;
    }
}

// K1: partial tanh-sums over an o-quarter.
// r16 post-mortem: per-CU pipe budget = LDS 15.4us + MFMA 12.4 + trans ~7 +
// VALU ~5 ~= 40 = measured -> LDS read traffic is now the LARGEST pipe and
// it scales with waves (A-frags re-read per 32 positions). Fix: nt=4
// (64 pos/wave) halves LDS/qb/vw reads per position -> LDS ~7.7us.
// (256,3): cap ~168 VGPR for the ~120-reg shape (r5 lesson: the 128 cap of
// (256,4) forces a spill). Single depth-6 chains x4 = r3-proven ILP.
// Keeps: 1 barrier, s_sleep stagger, setprio on MFMA, XCD grouping (r16).
__global__ __launch_bounds__(256, 3) void k_scores(
    const float* __restrict__ key,
    const ushort_t* __restrict__ Whi_f, const ushort_t* __restrict__ Wlo_f,
    const float* __restrict__ QB, const float* __restrict__ Va2,
    float* __restrict__ e_part)
{
    const int bx = blockIdx.x;            // 0..2047
    const int x  = bx & 7;                // XCD slot
    const int r  = (bx >> 3) & 3;         // o-quarter (siblings 8 apart: same XCD)
    const int g  = (bx >> 5) * 8 + x;     // (b,pc) group 0..511
    const int b  = g >> 4;                // batch
    const int pc = g & 15;                // 256-pos chunk
    const int wv = threadIdx.x >> 6;
    const int l  = threadIdx.x & 63;
    const int lm = l & 15;                // col-in-tile (A row / B,C col)
    const int kg = l >> 4;                // k-group
    const int p0 = pc * 256 + wv * 64;    // wave's first position

    __shared__ ushort_t Wl[16384];        // [hi 8K | lo 8K] ushorts: this r's 8 m-tiles
    __shared__ float qbl[OCHUNK];
    __shared__ float vwl[OCHUNK];

    // ---- stage W quarter: wave wv stages m-tiles {wv*2, wv*2+1} hi+lo ----
    const size_t wbase = ((size_t)r * MT + wv * 2) * 1024;   // ushort offset
#pragma unroll
    for (int t = 0; t < 4; ++t) {
        gld16(Whi_f + wbase + t * 512 + l * 8, &Wl[wv * 2048 + t * 512]);
        gld16(Wlo_f + wbase + t * 512 + l * 8, &Wl[8192 + wv * 2048 + t * 512]);
    }
    if (wv == 0) {                        // qb quarter: 128 floats
        gld4(QB + b * NP + r * OCHUNK + l, &qbl[0]);
        gld4(QB + b * NP + r * OCHUNK + 64 + l, &qbl[64]);
    }
    if (wv == 1) {                        // vw quarter: 128 floats
        gld4(Va2 + r * OCHUNK + l, &vwl[0]);
        gld4(Va2 + r * OCHUNK + 64 + l, &vwl[64]);
    }

    // ---- load + bf16-split this wave's key ONCE: B = key[b,:,p0..p0+63] ----
    short8 Bh[4][2], Bl8[4][2];
    const float* kb = key + (size_t)b * CH * HW;
#pragma unroll
    for (int nt = 0; nt < 4; ++nt) {
#pragma unroll
        for (int ks = 0; ks < 2; ++ks) {
#pragma unroll
            for (int j = 0; j < 8; ++j) {
                float xv = kb[(size_t)(ks * 32 + kg * 8 + j) * HW + (p0 + nt * 16 + lm)];
                ushort_t h = f2bf(xv);
                Bh[nt][ks][j]  = (short)h;
                Bl8[nt][ks][j] = (short)f2bf(xv - bf2f(h));
            }
        }
    }

    __syncthreads();                      // all staging drained; ONLY barrier

    // time-domain stagger: de-phase the block's waves (~320 cyc apart)
    if (wv == 1) __builtin_amdgcn_s_sleep(5);
    else if (wv == 2) __builtin_amdgcn_s_sleep(10);
    else if (wv == 3) __builtin_amdgcn_s_sleep(15);

    float P[4] = {0.0f, 0.0f, 0.0f, 0.0f};   // partial of (-2vw)*rcp

    // ---- 8 m-tiles, no barriers, no global ops ----
#pragma unroll 2
    for (int mt = 0; mt < MT; ++mt) {
        const short8 Ah0 = *(const short8*)&Wl[mt * 1024 + l * 8];
        const short8 Ah1 = *(const short8*)&Wl[mt * 1024 + 512 + l * 8];
        const short8 Al0 = *(const short8*)&Wl[8192 + mt * 1024 + l * 8];
        const short8 Al1 = *(const short8*)&Wl[8192 + mt * 1024 + 512 + l * 8];
        const f32x4 qb = *(const f32x4*)&qbl[mt * 16 + kg * 4];
        const f32x4 vw = *(const f32x4*)&vwl[mt * 16 + kg * 4];

        // 4 independent chains of depth 6; C-init = qb
        f32x4 acc[4];
        __builtin_amdgcn_s_setprio(1);
#pragma unroll
        for (int nt = 0; nt < 4; ++nt)
            acc[nt] = __builtin_amdgcn_mfma_f32_16x16x32_bf16(Ah0, Bh[nt][0], qb, 0, 0, 0);
#pragma unroll
        for (int nt = 0; nt < 4; ++nt)
            acc[nt] = __builtin_amdgcn_mfma_f32_16x16x32_bf16(Ah1, Bh[nt][1], acc[nt], 0, 0, 0);
#pragma unroll
        for (int nt = 0; nt < 4; ++nt)
            acc[nt] = __builtin_amdgcn_mfma_f32_16x16x32_bf16(Ah0, Bl8[nt][0], acc[nt], 0, 0, 0);
#pragma unroll
        for (int nt = 0; nt < 4; ++nt)
            acc[nt] = __builtin_amdgcn_mfma_f32_16x16x32_bf16(Ah1, Bl8[nt][1], acc[nt], 0, 0, 0);
#pragma unroll
        for (int nt = 0; nt < 4; ++nt)
            acc[nt] = __builtin_amdgcn_mfma_f32_16x16x32_bf16(Al0, Bh[nt][0], acc[nt], 0, 0, 0);
#pragma unroll
        for (int nt = 0; nt < 4; ++nt)
            acc[nt] = __builtin_amdgcn_mfma_f32_16x16x32_bf16(Al1, Bh[nt][1], acc[nt], 0, 0, 0);
        __builtin_amdgcn_s_setprio(0);

        // epilogue: s pre-scaled by 2*log2(e); P += (-2vw)*rcp(exp2(s)+1)
#pragma unroll
        for (int nt = 0; nt < 4; ++nt)
#pragma unroll
            for (int rr = 0; rr < 4; ++rr) {
                float e  = __builtin_amdgcn_exp2f(acc[nt][rr]);
                float rc = __builtin_amdgcn_rcpf(e + 1.0f);
                P[nt] = fmaf(vw[rr], rc, P[nt]);
            }
    }

    // reduce over the 4 k-groups; kg==0 lanes hold the quarter-sums
#pragma unroll
    for (int nt = 0; nt < 4; ++nt) {
        P[nt] += __shfl_xor(P[nt], 16, 64);
        P[nt] += __shfl_xor(P[nt], 32, 64);
    }
    if (kg == 0) {
        float* dst = e_part + (size_t)r * (BSZ * HW) + (size_t)b * HW + p0;
#pragma unroll
        for (int nt = 0; nt < 4; ++nt)
            dst[nt * 16 + lm] = P[nt];
    }
}

// K2: combine 4 o-quarters, exp, per-batch denominator.
__global__ __launch_bounds__(256) void k_denom(
    const float* __restrict__ e_part,
    const float* __restrict__ SUMVW, const float* __restrict__ Va_b,
    float* __restrict__ e_exp, float* __restrict__ inv_denom)
{
    const int b = blockIdx.x;
    const int tid = threadIdx.x;
    const float base = SUMVW[0] + Va_b[0];
    float s = 0.0f;
#pragma unroll
    for (int i = 0; i < HW / 256; ++i) {
        const int idx = b * HW + i * 256 + tid;
        float p = (e_part[idx] + e_part[BSZ * HW + idx]) +
                  (e_part[2 * BSZ * HW + idx] + e_part[3 * BSZ * HW + idx]);
        float e = __builtin_amdgcn_exp2f((p + base) * L2E);
        e_exp[idx] = e;
        s += e;
    }
#pragma unroll
    for (int off = 32; off > 0; off >>= 1) s += __shfl_down(s, off, 64);
    __shared__ float wsum[4];
    if ((tid & 63) == 0) wsum[tid >> 6] = s;
    __syncthreads();
    if (tid == 0) {
        float t = (wsum[0] + wsum[1]) + (wsum[2] + wsum[3]);
        inv_denom[b] = 1.0f / (t + EPS);
    }
}

// K3: out[b,c,p] = feature[b,c,p] * e_exp[b,p] * inv_denom[b]  (float4)
__global__ __launch_bounds__(256) void k_scale(
    const float* __restrict__ feature,
    const float* __restrict__ e_exp,
    const float* __restrict__ inv_denom,
    float* __restrict__ out)
{
    const int idx = blockIdx.x * 256 + threadIdx.x;   // float4 index
    const int pq = idx & (HW / 4 - 1);
    const int bc = idx >> 10;
    const int b  = bc >> 6;

    const float sc = inv_denom[b];
    const float4 e = ((const float4*)(e_exp + (size_t)b * HW))[pq];
    const float4 f = ((const float4*)feature)[idx];
    float4 o;
    o.x = f.x * (e.x * sc);
    o.y = f.y * (e.y * sc);
    o.z = f.z * (e.z * sc);
    o.w = f.w * (e.w * sc);
    ((float4*)out)[idx] = o;
}

extern "C" void kernel_launch(void* const* d_in, const int* in_sizes, int n_in,
                              void* d_out, int out_size, void* d_ws, size_t ws_size,
                              hipStream_t stream)
{
    const float* feature = (const float*)d_in[0];
    const float* query   = (const float*)d_in[1];
    const float* key     = (const float*)d_in[2];
    const float* Ua_w    = (const float*)d_in[3];
    const float* Ua_b    = (const float*)d_in[4];
    const float* Va_w    = (const float*)d_in[5];
    const float* Va_b    = (const float*)d_in[6];

    // workspace layout
    ushort_t* Whi_f = (ushort_t*)d_ws;                      // 512*64 frag-order
    ushort_t* Wlo_f = Whi_f + NP * CH;                      // 512*64
    float* QB        = (float*)(Wlo_f + NP * CH);           // 32*512
    float* Va2       = QB + BSZ * NP;                       // 512
    float* SUMVW     = Va2 + NP;                            // 1 (+pad)
    float* e_part    = SUMVW + 4;                           // 4*32*4096
    float* e_exp     = e_part + (size_t)OSPLIT * BSZ * HW;  // 32*4096
    float* inv_denom = e_exp + BSZ * HW;                    // 32

    k_prep<<<(NP * CH) / 256, 256, 0, stream>>>(
        Ua_w, Ua_b, query, Va_w, Whi_f, Wlo_f, QB, Va2, SUMVW);
    k_scores<<<BSZ * 16 * OSPLIT, 256, 0, stream>>>(
        key, Whi_f, Wlo_f, QB, Va2, e_part);
    k_denom<<<BSZ, 256, 0, stream>>>(e_part, SUMVW, Va_b, e_exp, inv_denom);
    k_scale<<<(BSZ * CH * HW / 4) / 256, 256, 0, stream>>>(
        feature, e_exp, inv_denom, (float*)d_out);
}

// Round 18
// 41.751 us; speedup vs baseline: 1.4039x; 1.2979x over previous
//
#include <hip/hip_runtime.h>

typedef unsigned short ushort_t;
typedef unsigned int uint_t;

constexpr int BSZ = 32;
constexpr int CH  = 64;
constexpr int HW  = 32 * 128;   // 4096
constexpr int NP  = 512;
constexpr int OSPLIT = 4;             // o-split across blocks
constexpr int OCHUNK = NP / OSPLIT;   // 128 o per block = 8 m-tiles
constexpr int MT     = OCHUNK / 16;   // 8
constexpr float EPS = 1e-8f;
constexpr float SCL = 2.8853900817779268f;   // 2*log2(e): pre-scale W,QB -> tanh needs no mul
constexpr float L2E = 1.4426950408889634f;   // log2(e)

using f16x8 = __attribute__((ext_vector_type(8))) _Float16;  // 8 fp16 (4 VGPRs)
using f32x4 = __attribute__((ext_vector_type(4))) float;

// async global->LDS (LDS dest = wave-uniform base + lane*size)
__device__ __forceinline__ void gld16(const void* g, void* l) {
    __builtin_amdgcn_global_load_lds(
        (const __attribute__((address_space(1))) void*)g,
        (__attribute__((address_space(3))) void*)l, 16, 0, 0);
}
__device__ __forceinline__ void gld4(const void* g, void* l) {
    __builtin_amdgcn_global_load_lds(
        (const __attribute__((address_space(1))) void*)g,
        (__attribute__((address_space(3))) void*)l, 4, 0, 0);
}

// K0: W' = SCL*Ua_w as SINGLE-PASS FP16 in MFMA-frag order.
// r17 post-mortem: every schedule lands on the serialized pipe-sum, so shrink
// the pipes algebraically. fp16 (11-bit mantissa) single-pass matmul keeps
// the logit error ~5e-4 relative -> output absmax ~1e-5 scale (bf16 single
// would be ~1.8e-4, too close to the 1.95e-4 threshold).
//   fidx = mt*1024 + ks*512 + (kg*16+lm)*8 + j   (mt = o>>4 = 0..31)
// QB = SCL*(query+Ua_b); Va2 = -2*Va_w; SUMVW = sum(Va_w).
__global__ __launch_bounds__(256) void k_prep(
    const float* __restrict__ Ua_w, const float* __restrict__ Ua_b,
    const float* __restrict__ query, const float* __restrict__ Va_w,
    ushort_t* __restrict__ Whf,
    float* __restrict__ QB, float* __restrict__ Va2, float* __restrict__ SUMVW)
{
    const int i = blockIdx.x * 256 + threadIdx.x;
    if (i < NP * CH) {
        const int o = i >> 6, ch = i & 63;
        const int mt = o >> 4, lm = o & 15;
        const int ks = ch >> 5, kg = (ch >> 3) & 3, j = ch & 7;
        const int fidx = mt * 1024 + ks * 512 + (kg * 16 + lm) * 8 + j;
        _Float16 h = (_Float16)(Ua_w[i] * SCL);
        Whf[fidx] = __builtin_bit_cast(ushort_t, h);
    }
    if (i < BSZ * NP) {
        QB[i] = SCL * (query[i] + Ua_b[i & (NP - 1)]);
    }
    if (i < NP) {
        Va2[i] = -2.0f * Va_w[i];
    }
    if (blockIdx.x == 0 && threadIdx.x < 64) {
        float s = 0.0f;
#pragma unroll
        for (int t = 0; t < 8; ++t) s += Va_w[threadIdx.x + t * 64];
#pragma unroll
        for (int off = 32; off > 0; off >>= 1) s += __shfl_down(s, off, 64);
        if (threadIdx.x == 0) SUMVW[0] = s;
    }
}

// K1: partial tanh-sums over an o-quarter, single-pass fp16 MFMA.
// Per mt: 8 MFMA (was 24), 2 A-frag ds_reads (was 4), B-frags 32 VGPR
// (was 64) -> (256,4) fits ~90 regs without spill. W quarter = 16KB LDS.
// Keeps r17's schedule: 1 barrier, s_sleep stagger, setprio, XCD grouping.
__global__ __launch_bounds__(256, 4) void k_scores(
    const float* __restrict__ key,
    const ushort_t* __restrict__ Whf,
    const float* __restrict__ QB, const float* __restrict__ Va2,
    float* __restrict__ e_part)
{
    const int bx = blockIdx.x;            // 0..2047
    const int x  = bx & 7;                // XCD slot
    const int r  = (bx >> 3) & 3;         // o-quarter (siblings 8 apart: same XCD)
    const int g  = (bx >> 5) * 8 + x;     // (b,pc) group 0..511
    const int b  = g >> 4;                // batch
    const int pc = g & 15;                // 256-pos chunk
    const int wv = threadIdx.x >> 6;
    const int l  = threadIdx.x & 63;
    const int lm = l & 15;                // col-in-tile (A row / B,C col)
    const int kg = l >> 4;                // k-group
    const int p0 = pc * 256 + wv * 64;    // wave's first position

    __shared__ ushort_t Wl[8192];         // this r's 8 m-tiles, fp16 frag order (16KB)
    __shared__ float qbl[OCHUNK];
    __shared__ float vwl[OCHUNK];

    // ---- stage W quarter: wave wv stages m-tiles {wv*2, wv*2+1} ----
    const size_t wbase = ((size_t)r * MT + wv * 2) * 1024;   // ushort offset
#pragma unroll
    for (int t = 0; t < 4; ++t)
        gld16(Whf + wbase + t * 512 + l * 8, &Wl[wv * 2048 + t * 512]);
    if (wv == 0) {                        // qb quarter: 128 floats
        gld4(QB + b * NP + r * OCHUNK + l, &qbl[0]);
        gld4(QB + b * NP + r * OCHUNK + 64 + l, &qbl[64]);
    }
    if (wv == 1) {                        // vw quarter: 128 floats
        gld4(Va2 + r * OCHUNK + l, &vwl[0]);
        gld4(Va2 + r * OCHUNK + 64 + l, &vwl[64]);
    }

    // ---- load + fp16-convert this wave's key ONCE: B = key[b,:,p0..p0+63] ----
    f16x8 Bh[4][2];
    const float* kb = key + (size_t)b * CH * HW;
#pragma unroll
    for (int nt = 0; nt < 4; ++nt) {
#pragma unroll
        for (int ks = 0; ks < 2; ++ks) {
#pragma unroll
            for (int j = 0; j < 8; ++j) {
                float xv = kb[(size_t)(ks * 32 + kg * 8 + j) * HW + (p0 + nt * 16 + lm)];
                Bh[nt][ks][j] = (_Float16)xv;
            }
        }
    }

    __syncthreads();                      // all staging drained; ONLY barrier

    // time-domain stagger: de-phase the block's waves (~320 cyc apart)
    if (wv == 1) __builtin_amdgcn_s_sleep(5);
    else if (wv == 2) __builtin_amdgcn_s_sleep(10);
    else if (wv == 3) __builtin_amdgcn_s_sleep(15);

    float P[4] = {0.0f, 0.0f, 0.0f, 0.0f};   // partial of (-2vw)*rcp

    // ---- 8 m-tiles, no barriers, no global ops ----
#pragma unroll 2
    for (int mt = 0; mt < MT; ++mt) {
        const f16x8 Ah0 = *(const f16x8*)&Wl[mt * 1024 + l * 8];
        const f16x8 Ah1 = *(const f16x8*)&Wl[mt * 1024 + 512 + l * 8];
        const f32x4 qb = *(const f32x4*)&qbl[mt * 16 + kg * 4];
        const f32x4 vw = *(const f32x4*)&vwl[mt * 16 + kg * 4];

        // 4 independent chains of depth 2; C-init = qb
        f32x4 acc[4];
        __builtin_amdgcn_s_setprio(1);
#pragma unroll
        for (int nt = 0; nt < 4; ++nt)
            acc[nt] = __builtin_amdgcn_mfma_f32_16x16x32_f16(Ah0, Bh[nt][0], qb, 0, 0, 0);
#pragma unroll
        for (int nt = 0; nt < 4; ++nt)
            acc[nt] = __builtin_amdgcn_mfma_f32_16x16x32_f16(Ah1, Bh[nt][1], acc[nt], 0, 0, 0);
        __builtin_amdgcn_s_setprio(0);

        // epilogue: s pre-scaled by 2*log2(e); P += (-2vw)*rcp(exp2(s)+1)
#pragma unroll
        for (int nt = 0; nt < 4; ++nt)
#pragma unroll
            for (int rr = 0; rr < 4; ++rr) {
                float e  = __builtin_amdgcn_exp2f(acc[nt][rr]);
                float rc = __builtin_amdgcn_rcpf(e + 1.0f);
                P[nt] = fmaf(vw[rr], rc, P[nt]);
            }
    }

    // reduce over the 4 k-groups; kg==0 lanes hold the quarter-sums
#pragma unroll
    for (int nt = 0; nt < 4; ++nt) {
        P[nt] += __shfl_xor(P[nt], 16, 64);
        P[nt] += __shfl_xor(P[nt], 32, 64);
    }
    if (kg == 0) {
        float* dst = e_part + (size_t)r * (BSZ * HW) + (size_t)b * HW + p0;
#pragma unroll
        for (int nt = 0; nt < 4; ++nt)
            dst[nt * 16 + lm] = P[nt];
    }
}

// K2: combine 4 o-quarters, exp, per-batch denominator.
__global__ __launch_bounds__(256) void k_denom(
    const float* __restrict__ e_part,
    const float* __restrict__ SUMVW, const float* __restrict__ Va_b,
    float* __restrict__ e_exp, float* __restrict__ inv_denom)
{
    const int b = blockIdx.x;
    const int tid = threadIdx.x;
    const float base = SUMVW[0] + Va_b[0];
    float s = 0.0f;
#pragma unroll
    for (int i = 0; i < HW / 256; ++i) {
        const int idx = b * HW + i * 256 + tid;
        float p = (e_part[idx] + e_part[BSZ * HW + idx]) +
                  (e_part[2 * BSZ * HW + idx] + e_part[3 * BSZ * HW + idx]);
        float e = __builtin_amdgcn_exp2f((p + base) * L2E);
        e_exp[idx] = e;
        s += e;
    }
#pragma unroll
    for (int off = 32; off > 0; off >>= 1) s += __shfl_down(s, off, 64);
    __shared__ float wsum[4];
    if ((tid & 63) == 0) wsum[tid >> 6] = s;
    __syncthreads();
    if (tid == 0) {
        float t = (wsum[0] + wsum[1]) + (wsum[2] + wsum[3]);
        inv_denom[b] = 1.0f / (t + EPS);
    }
}

// K3: out[b,c,p] = feature[b,c,p] * e_exp[b,p] * inv_denom[b]  (float4)
__global__ __launch_bounds__(256) void k_scale(
    const float* __restrict__ feature,
    const float* __restrict__ e_exp,
    const float* __restrict__ inv_denom,
    float* __restrict__ out)
{
    const int idx = blockIdx.x * 256 + threadIdx.x;   // float4 index
    const int pq = idx & (HW / 4 - 1);
    const int bc = idx >> 10;
    const int b  = bc >> 6;

    const float sc = inv_denom[b];
    const float4 e = ((const float4*)(e_exp + (size_t)b * HW))[pq];
    const float4 f = ((const float4*)feature)[idx];
    float4 o;
    o.x = f.x * (e.x * sc);
    o.y = f.y * (e.y * sc);
    o.z = f.z * (e.z * sc);
    o.w = f.w * (e.w * sc);
    ((float4*)out)[idx] = o;
}

extern "C" void kernel_launch(void* const* d_in, const int* in_sizes, int n_in,
                              void* d_out, int out_size, void* d_ws, size_t ws_size,
                              hipStream_t stream)
{
    const float* feature = (const float*)d_in[0];
    const float* query   = (const float*)d_in[1];
    const float* key     = (const float*)d_in[2];
    const float* Ua_w    = (const float*)d_in[3];
    const float* Ua_b    = (const float*)d_in[4];
    const float* Va_w    = (const float*)d_in[5];
    const float* Va_b    = (const float*)d_in[6];

    // workspace layout
    ushort_t* Whf   = (ushort_t*)d_ws;                      // 512*64 fp16 frag-order
    float* QB        = (float*)(Whf + NP * CH);             // 32*512
    float* Va2       = QB + BSZ * NP;                       // 512
    float* SUMVW     = Va2 + NP;                            // 1 (+pad)
    float* e_part    = SUMVW + 4;                           // 4*32*4096
    float* e_exp     = e_part + (size_t)OSPLIT * BSZ * HW;  // 32*4096
    float* inv_denom = e_exp + BSZ * HW;                    // 32

    k_prep<<<(NP * CH) / 256, 256, 0, stream>>>(
        Ua_w, Ua_b, query, Va_w, Whf, QB, Va2, SUMVW);
    k_scores<<<BSZ * 16 * OSPLIT, 256, 0, stream>>>(
        key, Whf, QB, Va2, e_part);
    k_denom<<<BSZ, 256, 0, stream>>>(e_part, SUMVW, Va_b, e_exp, inv_denom);
    k_scale<<<(BSZ * CH * HW / 4) / 256, 256, 0, stream>>>(
        feature, e_exp, inv_denom, (float*)d_out);
}